// Round 2
// baseline (1115.123 us; speedup 1.0000x reference)
//
#include <hip/hip_runtime.h>
#include <cstdint>

// LWMCrossAttention fused kernel for MI355X (gfx950) — v2 (resubmit; round-1
// bench failed on GPU acquisition, no counters).
// Phase-reordered (k/v first, q streamed) so no qn state is held across phases;
// 32 KB half-window LDS staging -> 4 blocks/CU; swapped-operand q projection;
// XCD-chunked block swizzle; float4 stores.

typedef short V8AB __attribute__((ext_vector_type(8)));
typedef float V4F  __attribute__((ext_vector_type(4)));

#define IMG_W   256
#define HWSZ    65536       // 256*256
#define CCH     128
#define EPSF    1e-6f

__device__ __forceinline__ unsigned short f2bits(float f) {
    return __builtin_bit_cast(unsigned short, (__bf16)f);   // RNE
}

// W-operand fragment: frag[m=lane&15 -> weight row][k=(lane>>4)*8+j -> 8 cols].
__device__ __forceinline__ V8AB load_wfrag(const float* __restrict__ wrow) {
    float4 w0 = *(const float4*)(wrow);
    float4 w1 = *(const float4*)(wrow + 4);
    V8AB r;
    r[0] = (short)f2bits(w0.x); r[1] = (short)f2bits(w0.y);
    r[2] = (short)f2bits(w0.z); r[3] = (short)f2bits(w0.w);
    r[4] = (short)f2bits(w1.x); r[5] = (short)f2bits(w1.y);
    r[6] = (short)f2bits(w1.z); r[7] = (short)f2bits(w1.w);
    return r;
}

// Stage half a window (128 ch x 128 tok, fp32 channel-major -> bf16 chunks, 32 KB).
// chunk#(t,c0) = (t>>4)*256 + (c0>>5)*64 + ((c0>>3)&3)*16 + (t&15); chunk = 16 B.
// Fragment read at (tile, ks, lane) is chunk# = tile*256 + ks*64 + lane (lane-linear).
__device__ __forceinline__ void stage_half(const float* __restrict__ src,
                                           short* xbuf, int tid, int pixbase) {
    #pragma unroll
    for (int it = 0; it < 4; ++it) {
        int p  = it * 256 + tid;        // pair id, 0..1023
        int t0 = 2 * (p & 63);          // local token 0..126, even
        int cg = p >> 6;                // channel group 0..15 (8 ch each)
        int c0 = cg * 8;
        const float* g = src + (size_t)c0 * HWSZ + pixbase + (t0 >> 4) * IMG_W + (t0 & 15);
        float2 f[8];
        #pragma unroll
        for (int j = 0; j < 8; ++j)
            f[j] = *(const float2*)(g + (size_t)j * HWSZ);
        V8AB va, vb;
        #pragma unroll
        for (int j = 0; j < 8; ++j) {
            va[j] = (short)f2bits(f[j].x);   // token t0
            vb[j] = (short)f2bits(f[j].y);   // token t0+1
        }
        int ca = ((t0 >> 4) << 8) + ((cg >> 2) << 6) + ((cg & 3) << 4) + (t0 & 15);
        *(V8AB*)(xbuf + (size_t)ca * 8)       = va;
        *(V8AB*)(xbuf + (size_t)(ca + 1) * 8) = vb;
    }
}

__global__ __launch_bounds__(256, 4)
void lwm_fused_kernel(const float* __restrict__ x1, const float* __restrict__ x2,
                      const float* __restrict__ Wq, const float* __restrict__ Wkv,
                      float* __restrict__ out) {
    __shared__ __align__(16) short xbuf[16384];   // 32 KB: 2048 chunks x 16 B

    const int tid  = threadIdx.x;
    const int lane = tid & 63;
    const int wv   = tid >> 6;        // wave 0..3, owns heads wv and wv+4
    const int l15  = lane & 15;
    const int quad = lane >> 4;
    const int zhi  = quad >> 1;       // 1 for quads 2,3 (zero K-half of K=32 mfmas)

    // XCD-chunked swizzle: 2048 wgs, 8 XCDs -> XCD k owns batch image k,
    // adjacent windows (sharing 128B HBM lines) stay on one XCD's L2.
    const int bid = blockIdx.x;
    const int blk = ((bid & 7) << 8) | (bid >> 3);
    const int b   = blk >> 8;
    const int wy  = (blk >> 4) & 15;
    const int wx  = blk & 15;
    const int pixbase = wy * 16 * IMG_W + wx * 16;

    const float* x1b  = x1 + (size_t)b * CCH * HWSZ;
    const float* x2b  = x2 + (size_t)b * CCH * HWSZ;
    float*       outb = out + (size_t)b * CCH * HWSZ;

    // ================= Phase A: x2 -> k,v ; accumulate kvacc/ksum/vsum =========
    float ksum[2] = {0.f, 0.f}, vsum[2] = {0.f, 0.f};
    V4F kvacc[2] = {{0.f,0.f,0.f,0.f},{0.f,0.f,0.f,0.f}};

    #pragma unroll
    for (int half = 0; half < 2; ++half) {
        stage_half(x2b, xbuf, tid, pixbase + half * (8 * IMG_W));
        __syncthreads();
        #pragma unroll
        for (int hh = 0; hh < 2; ++hh) {
            const int head = wv + 4 * hh;
            V8AB bk[4], bv[4];
            #pragma unroll
            for (int ks = 0; ks < 4; ++ks) {
                bk[ks] = load_wfrag(Wkv + (size_t)(head * 16 + l15) * CCH + ks * 32 + quad * 8);
                bv[ks] = load_wfrag(Wkv + (size_t)(CCH + head * 16 + l15) * CCH + ks * 32 + quad * 8);
            }
            #pragma unroll
            for (int s2 = 0; s2 < 4; ++s2) {     // token-tile pairs (32 tokens)
                V4F aK0 = {0,0,0,0}, aK1 = {0,0,0,0}, aV0 = {0,0,0,0}, aV1 = {0,0,0,0};
                #pragma unroll
                for (int ks = 0; ks < 4; ++ks) {
                    V8AB a0 = *(const V8AB*)(xbuf + (size_t)((2*s2    ) * 256 + ks * 64 + lane) * 8);
                    V8AB a1 = *(const V8AB*)(xbuf + (size_t)((2*s2 + 1) * 256 + ks * 64 + lane) * 8);
                    aK0 = __builtin_amdgcn_mfma_f32_16x16x32_bf16(a0, bk[ks], aK0, 0, 0, 0);
                    aV0 = __builtin_amdgcn_mfma_f32_16x16x32_bf16(a0, bv[ks], aV0, 0, 0, 0);
                    aK1 = __builtin_amdgcn_mfma_f32_16x16x32_bf16(a1, bk[ks], aK1, 0, 0, 0);
                    aV1 = __builtin_amdgcn_mfma_f32_16x16x32_bf16(a1, bv[ks], aV1, 0, 0, 0);
                }
                // token-major D: [tok=quad*4+r][ch=l15]; normalize k, pack kn/v early.
                unsigned pk0[2], pk1[2], pv0[2], pv1[2];
                #pragma unroll
                for (int r = 0; r < 4; ++r) {
                    float s = aK0[r] * aK0[r];
                    s += __shfl_xor(s, 1); s += __shfl_xor(s, 2);
                    s += __shfl_xor(s, 4); s += __shfl_xor(s, 8);
                    float kn0 = aK0[r] * rsqrtf(s);
                    float t = aK1[r] * aK1[r];
                    t += __shfl_xor(t, 1); t += __shfl_xor(t, 2);
                    t += __shfl_xor(t, 4); t += __shfl_xor(t, 8);
                    float kn1 = aK1[r] * rsqrtf(t);
                    ksum[hh] += kn0 + kn1;
                    vsum[hh] += aV0[r] + aV1[r];
                    unsigned uk0 = f2bits(kn0),     uk1 = f2bits(kn1);
                    unsigned uv0 = f2bits(aV0[r]),  uv1 = f2bits(aV1[r]);
                    if ((r & 1) == 0) {
                        pk0[r >> 1] = uk0;  pk1[r >> 1] = uk1;
                        pv0[r >> 1] = uv0;  pv1[r >> 1] = uv1;
                    } else {
                        pk0[r >> 1] |= uk0 << 16;  pk1[r >> 1] |= uk1 << 16;
                        pv0[r >> 1] |= uv0 << 16;  pv1[r >> 1] |= uv1 << 16;
                    }
                }
                // kv_acc operands: A[m=ck=l15][k=tok], B[k=tok][n=cv=l15]
                V8AB ka, vb;
                #pragma unroll
                for (int j = 0; j < 8; ++j) {
                    int src = l15 + ((((quad & 1) * 2) + (j >> 2)) << 4);
                    unsigned k0 = __shfl(pk0[(j >> 1) & 1], src);
                    unsigned k1 = __shfl(pk1[(j >> 1) & 1], src);
                    unsigned v0 = __shfl(pv0[(j >> 1) & 1], src);
                    unsigned v1 = __shfl(pv1[(j >> 1) & 1], src);
                    unsigned ku = zhi ? k1 : k0;
                    unsigned vu = zhi ? v1 : v0;
                    ka[j] = (short)((j & 1) ? (ku >> 16) : (ku & 0xffffu));
                    vb[j] = (short)((j & 1) ? (vu >> 16) : (vu & 0xffffu));
                }
                kvacc[hh] = __builtin_amdgcn_mfma_f32_16x16x32_bf16(ka, vb, kvacc[hh], 0, 0, 0);
            }
        }
        __syncthreads();
    }

    // ================= finalize per head: kvb, vsum, ksf4 =====================
    V8AB  kvb[2];
    float ksf4[2][4];
    float vs[2];
    #pragma unroll
    for (int hh = 0; hh < 2; ++hh) {
        float ks_ = ksum[hh];
        ks_ += __shfl_xor(ks_, 16); ks_ += __shfl_xor(ks_, 32);
        float vs_ = vsum[hh];
        vs_ += __shfl_xor(vs_, 16); vs_ += __shfl_xor(vs_, 32);
        vs[hh] = vs_;
        const float ksf = ks_ + EPSF;            // per-channel (ch = l15)
        // kvacc D[ck=quad*4+r][cv=l15] -> attn B-frag [k=ck][n=cv], rows 16..31 zero
        #pragma unroll
        for (int j = 0; j < 8; ++j) {
            int src = l15 + ((((quad & 1) * 2) + (j >> 2)) << 4);
            float kv = __shfl(kvacc[hh][j & 3], src);
            kvb[hh][j] = zhi ? (short)0 : (short)f2bits(kv);
        }
        // ksf for my quad's 4 channels (quad*4+r), for the tailor dot
        #pragma unroll
        for (int r = 0; r < 4; ++r)
            ksf4[hh][r] = __shfl(ksf, quad * 4 + r);
    }

    // ================= Phase B: x1 -> q (swapped mfma) ; attn ; store =========
    #pragma unroll
    for (int half = 0; half < 2; ++half) {
        stage_half(x1b, xbuf, tid, pixbase + half * (8 * IMG_W));
        __syncthreads();
        #pragma unroll
        for (int hh = 0; hh < 2; ++hh) {
            const int head = wv + 4 * hh;
            V8AB bq[4];
            #pragma unroll
            for (int ks = 0; ks < 4; ++ks)
                bq[ks] = load_wfrag(Wq + (size_t)(head * 16 + l15) * CCH + ks * 32 + quad * 8);
            #pragma unroll
            for (int mtl = 0; mtl < 8; ++mtl) {
                // swapped: A=W, B=x  ->  D[ch=quad*4+r][tok=l15]
                V4F acc = {0,0,0,0};
                #pragma unroll
                for (int ks = 0; ks < 4; ++ks) {
                    V8AB a = *(const V8AB*)(xbuf + (size_t)(mtl * 256 + ks * 64 + lane) * 8);
                    acc = __builtin_amdgcn_mfma_f32_16x16x32_bf16(bq[ks], a, acc, 0, 0, 0);
                }
                // per-token norm over 16 ch: 4 in-lane + cross-quad
                float s = acc[0]*acc[0] + acc[1]*acc[1] + acc[2]*acc[2] + acc[3]*acc[3];
                s += __shfl_xor(s, 16); s += __shfl_xor(s, 32);
                const float rn = rsqrtf(s);
                const float qn0 = acc[0]*rn, qn1 = acc[1]*rn, qn2 = acc[2]*rn, qn3 = acc[3]*rn;
                // tailor dot: pd(tok=l15) = sum_ch qn*ksf  (f32, pre-pack)
                float pd = qn0*ksf4[hh][0] + qn1*ksf4[hh][1] + qn2*ksf4[hh][2] + qn3*ksf4[hh][3];
                pd += __shfl_xor(pd, 16); pd += __shfl_xor(pd, 32);
                const float ta = 1.0f / (256.0f + pd);
                // qa A-frag [m=tok=l15][k=ch=quad*8+j] via packed shuffles
                const unsigned pq0 = (unsigned)f2bits(qn0) | ((unsigned)f2bits(qn1) << 16);
                const unsigned pq1 = (unsigned)f2bits(qn2) | ((unsigned)f2bits(qn3) << 16);
                V8AB qa;
                #pragma unroll
                for (int j = 0; j < 8; ++j) {
                    int src = l15 + ((((quad & 1) * 2) + (j >> 2)) << 4);
                    unsigned u  = __shfl(((j >> 1) & 1) ? pq1 : pq0, src);
                    unsigned hs = (j & 1) ? (u >> 16) : (u & 0xffffu);
                    qa[j] = zhi ? (short)0 : (short)hs;
                }
                V4F z = {0,0,0,0};
                V4F d = __builtin_amdgcn_mfma_f32_16x16x32_bf16(qa, kvb[hh], z, 0, 0, 0);
                // D[tok=quad*4+r][ch=l15]; one float4 store per lane
                float4 o;
                o.x = (d[0] + vs[hh]) * __shfl(ta, quad * 4 + 0);
                o.y = (d[1] + vs[hh]) * __shfl(ta, quad * 4 + 1);
                o.z = (d[2] + vs[hh]) * __shfl(ta, quad * 4 + 2);
                o.w = (d[3] + vs[hh]) * __shfl(ta, quad * 4 + 3);
                const int mt = half * 8 + mtl;
                *(float4*)(outb + (size_t)(head * 16 + l15) * HWSZ + pixbase + mt * IMG_W + quad * 4) = o;
            }
        }
        if (half == 0) __syncthreads();
    }
}

extern "C" void kernel_launch(void* const* d_in, const int* in_sizes, int n_in,
                              void* d_out, int out_size, void* d_ws, size_t ws_size,
                              hipStream_t stream) {
    const float* x1  = (const float*)d_in[0];
    const float* x2  = (const float*)d_in[1];
    const float* Wq  = (const float*)d_in[2];
    const float* Wkv = (const float*)d_in[3];
    float* out = (float*)d_out;
    lwm_fused_kernel<<<dim3(2048), dim3(256), 0, stream>>>(x1, x2, Wq, Wkv, out);
}